// Round 1
// baseline (1830.071 us; speedup 1.0000x reference)
//
#include <hip/hip_runtime.h>
#include <math.h>

#define NN 100000
#define NE 1600000
#define INF_ 256
#define NH 4
#define DH 32
#define NHD 128
#define NEG_SLOPE 0.2f

__device__ __forceinline__ unsigned fenc(float f) {
    unsigned u = __float_as_uint(f);
    return (u & 0x80000000u) ? ~u : (u | 0x80000000u);
}
__device__ __forceinline__ float fdec(unsigned u) {
    unsigned b = (u & 0x80000000u) ? (u & 0x7FFFFFFFu) : ~u;
    return __uint_as_float(b);
}

// ---------------- GEMM: feat [NN,256] x W[128,256]^T -> fs [NN,128] ----------
__global__ __launch_bounds__(256) void k_gemm(const float* __restrict__ feat,
                                              const float* __restrict__ W,
                                              float* __restrict__ fs) {
    __shared__ float As[64][33];
    __shared__ float Bs[32][132];
    const int block_row = blockIdx.x * 64;
    const int t = threadIdx.x;
    const int tr = t >> 4;   // 0..15
    const int tc = t & 15;   // 0..15

    float acc[4][8];
#pragma unroll
    for (int i = 0; i < 4; i++)
#pragma unroll
        for (int j = 0; j < 8; j++) acc[i][j] = 0.f;

    for (int k0 = 0; k0 < INF_; k0 += 32) {
        // A tile: thread loads 8 floats, row = t/4, k = (t%4)*8
        {
            int r = t >> 2;
            int kk = (t & 3) << 3;
            int gr = block_row + r;
            float4 v0 = make_float4(0, 0, 0, 0), v1 = make_float4(0, 0, 0, 0);
            if (gr < NN) {
                v0 = *(const float4*)&feat[(size_t)gr * INF_ + k0 + kk];
                v1 = *(const float4*)&feat[(size_t)gr * INF_ + k0 + kk + 4];
            }
            *(float4*)&As[r][kk] = v0;
            *(float4*)&As[r][kk + 4] = v1;
        }
        // B tile: Bs[k][col] = W[col][k0+k]
#pragma unroll
        for (int i = 0; i < 4; i++) {
            int col = i * 32 + (t >> 3);
            int kk = (t & 7) << 2;
            float4 v = *(const float4*)&W[(size_t)col * INF_ + k0 + kk];
            Bs[kk + 0][col] = v.x;
            Bs[kk + 1][col] = v.y;
            Bs[kk + 2][col] = v.z;
            Bs[kk + 3][col] = v.w;
        }
        __syncthreads();
#pragma unroll
        for (int k = 0; k < 32; k++) {
            float a[4], b[8];
#pragma unroll
            for (int i = 0; i < 4; i++) a[i] = As[tr * 4 + i][k];
#pragma unroll
            for (int j = 0; j < 8; j++) b[j] = Bs[k][tc + 16 * j];
#pragma unroll
            for (int i = 0; i < 4; i++)
#pragma unroll
                for (int j = 0; j < 8; j++) acc[i][j] += a[i] * b[j];
        }
        __syncthreads();
    }
#pragma unroll
    for (int i = 0; i < 4; i++) {
        int gr = block_row + tr * 4 + i;
        if (gr < NN) {
#pragma unroll
            for (int j = 0; j < 8; j++) fs[(size_t)gr * NHD + tc + 16 * j] = acc[i][j];
        }
    }
}

// ---------------- el/er per (node, head) ------------------------------------
__global__ __launch_bounds__(256) void k_elr(const float* __restrict__ fs,
                                             const float* __restrict__ al,
                                             const float* __restrict__ ar,
                                             float* __restrict__ el,
                                             float* __restrict__ er) {
    int i = blockIdx.x * blockDim.x + threadIdx.x;  // node*NH + h
    if (i >= NN * NH) return;
    int h = i & 3;
    const float* p = fs + (size_t)i * DH;
    float sl = 0.f, sr = 0.f;
#pragma unroll
    for (int d = 0; d < DH; d += 4) {
        float4 v = *(const float4*)&p[d];
        float4 l = *(const float4*)&al[h * DH + d];
        float4 r = *(const float4*)&ar[h * DH + d];
        sl += v.x * l.x + v.y * l.y + v.z * l.z + v.w * l.w;
        sr += v.x * r.x + v.y * r.y + v.z * r.z + v.w * r.w;
    }
    el[i] = sl;
    er[i] = sr;
}

// ---------------- edge pass 1: segment max ----------------------------------
__global__ __launch_bounds__(256) void k_edge_max(const int* __restrict__ src,
                                                  const int* __restrict__ dst,
                                                  const float* __restrict__ el,
                                                  const float* __restrict__ er,
                                                  unsigned* __restrict__ emax) {
    int e = blockIdx.x * blockDim.x + threadIdx.x;
    if (e >= NE) return;
    int s = src[e], d = dst[e];
    float4 l = *(const float4*)&el[(size_t)s * 4];
    float4 r = *(const float4*)&er[(size_t)d * 4];
    float v0 = l.x + r.x, v1 = l.y + r.y, v2 = l.z + r.z, v3 = l.w + r.w;
    v0 = v0 > 0.f ? v0 : NEG_SLOPE * v0;
    v1 = v1 > 0.f ? v1 : NEG_SLOPE * v1;
    v2 = v2 > 0.f ? v2 : NEG_SLOPE * v2;
    v3 = v3 > 0.f ? v3 : NEG_SLOPE * v3;
    atomicMax(&emax[(size_t)d * 4 + 0], fenc(v0));
    atomicMax(&emax[(size_t)d * 4 + 1], fenc(v1));
    atomicMax(&emax[(size_t)d * 4 + 2], fenc(v2));
    atomicMax(&emax[(size_t)d * 4 + 3], fenc(v3));
}

// ---------------- edge pass 2: exp + denom + numerator scatter ---------------
// one wave (64 lanes) per edge; lane covers 2 of the 128 feature floats
__global__ __launch_bounds__(256) void k_edge_acc(const int* __restrict__ src,
                                                  const int* __restrict__ dst,
                                                  const float* __restrict__ el,
                                                  const float* __restrict__ er,
                                                  const unsigned* __restrict__ emax,
                                                  const float* __restrict__ fs,
                                                  float* __restrict__ denom,
                                                  float* __restrict__ out) {
    long long gid = (long long)blockIdx.x * blockDim.x + threadIdx.x;
    int e = (int)(gid >> 6);
    int lane = (int)(gid & 63);
    if (e >= NE) return;
    int s = src[e], d = dst[e];
    int dbase = d * 4;
    int dd = lane * 2;       // 0..126
    int h = dd >> 5;
    float ev = el[s * 4 + h] + er[dbase + h];
    ev = ev > 0.f ? ev : NEG_SLOPE * ev;
    float m = fdec(emax[dbase + h]);
    if (!isfinite(m)) m = 0.f;
    float ee = __expf(ev - m);
    if ((dd & 31) == 0) atomicAdd(&denom[dbase + h], ee);
    float2 v = *(const float2*)&fs[(size_t)s * NHD + dd];
    atomicAdd(&out[(size_t)d * NHD + dd], ee * v.x);
    atomicAdd(&out[(size_t)d * NHD + dd + 1], ee * v.y);
}

// ---------------- finalize: divide by denom ---------------------------------
__global__ __launch_bounds__(256) void k_final(float* __restrict__ out,
                                               const float* __restrict__ denom) {
    int i = blockIdx.x * blockDim.x + threadIdx.x;  // node*NH + h
    if (i >= NN * NH) return;
    float dn = denom[i];
    float inv = dn > 0.f ? 1.0f / dn : 0.f;
    float4* p = (float4*)&out[(size_t)i * DH];
#pragma unroll
    for (int j = 0; j < 8; j++) {
        float4 v = p[j];
        v.x *= inv; v.y *= inv; v.z *= inv; v.w *= inv;
        p[j] = v;
    }
}

extern "C" void kernel_launch(void* const* d_in, const int* in_sizes, int n_in,
                              void* d_out, int out_size, void* d_ws, size_t ws_size,
                              hipStream_t stream) {
    const float* feat = (const float*)d_in[0];
    const int* src = (const int*)d_in[1];
    const int* dst = (const int*)d_in[2];
    const float* W = (const float*)d_in[3];
    const float* al = (const float*)d_in[4];
    const float* ar = (const float*)d_in[5];
    float* out = (float*)d_out;

    float* ws = (float*)d_ws;
    float* fs = ws;                       // NN*128 = 12.8M floats
    float* el = ws + (size_t)NN * NHD;    // NN*4
    float* er = el + (size_t)NN * NH;     // NN*4
    unsigned* emax = (unsigned*)(er + (size_t)NN * NH);  // NN*4
    float* denom = (float*)(emax + (size_t)NN * NH);     // NN*4

    hipMemsetAsync(d_out, 0, (size_t)out_size * sizeof(float), stream);
    hipMemsetAsync(emax, 0, (size_t)NN * NH * sizeof(unsigned), stream);  // 0 == encoded minimum
    hipMemsetAsync(denom, 0, (size_t)NN * NH * sizeof(float), stream);

    k_gemm<<<(NN + 63) / 64, 256, 0, stream>>>(feat, W, fs);
    k_elr<<<(NN * NH + 255) / 256, 256, 0, stream>>>(fs, al, ar, el, er);
    k_edge_max<<<(NE + 255) / 256, 256, 0, stream>>>(src, dst, el, er, emax);
    k_edge_acc<<<NE / 4, 256, 0, stream>>>(src, dst, el, er, emax, fs, denom, out);
    k_final<<<(NN * NH + 255) / 256, 256, 0, stream>>>(out, denom);
}

// Round 2
// 679.837 us; speedup vs baseline: 2.6919x; 2.6919x over previous
//
#include <hip/hip_runtime.h>
#include <math.h>

#define NN 100000
#define NE 1600000
#define INF_ 256
#define NH 4
#define DH 32
#define NHD 128
#define NEG_SLOPE 0.2f

// ---------------- GEMM: feat [NN,256] x W[128,256]^T -> fs [NN,128] ----------
__global__ __launch_bounds__(256) void k_gemm(const float* __restrict__ feat,
                                              const float* __restrict__ W,
                                              float* __restrict__ fs) {
    __shared__ float As[64][33];
    __shared__ float Bs[32][132];
    const int block_row = blockIdx.x * 64;
    const int t = threadIdx.x;
    const int tr = t >> 4;   // 0..15
    const int tc = t & 15;   // 0..15

    float acc[4][8];
#pragma unroll
    for (int i = 0; i < 4; i++)
#pragma unroll
        for (int j = 0; j < 8; j++) acc[i][j] = 0.f;

    for (int k0 = 0; k0 < INF_; k0 += 32) {
        {
            int r = t >> 2;
            int kk = (t & 3) << 3;
            int gr = block_row + r;
            float4 v0 = make_float4(0, 0, 0, 0), v1 = make_float4(0, 0, 0, 0);
            if (gr < NN) {
                v0 = *(const float4*)&feat[(size_t)gr * INF_ + k0 + kk];
                v1 = *(const float4*)&feat[(size_t)gr * INF_ + k0 + kk + 4];
            }
            *(float4*)&As[r][kk] = v0;
            *(float4*)&As[r][kk + 4] = v1;
        }
#pragma unroll
        for (int i = 0; i < 4; i++) {
            int col = i * 32 + (t >> 3);
            int kk = (t & 7) << 2;
            float4 v = *(const float4*)&W[(size_t)col * INF_ + k0 + kk];
            Bs[kk + 0][col] = v.x;
            Bs[kk + 1][col] = v.y;
            Bs[kk + 2][col] = v.z;
            Bs[kk + 3][col] = v.w;
        }
        __syncthreads();
#pragma unroll
        for (int k = 0; k < 32; k++) {
            float a[4], b[8];
#pragma unroll
            for (int i = 0; i < 4; i++) a[i] = As[tr * 4 + i][k];
#pragma unroll
            for (int j = 0; j < 8; j++) b[j] = Bs[k][tc + 16 * j];
#pragma unroll
            for (int i = 0; i < 4; i++)
#pragma unroll
                for (int j = 0; j < 8; j++) acc[i][j] += a[i] * b[j];
        }
        __syncthreads();
    }
#pragma unroll
    for (int i = 0; i < 4; i++) {
        int gr = block_row + tr * 4 + i;
        if (gr < NN) {
#pragma unroll
            for (int j = 0; j < 8; j++) fs[(size_t)gr * NHD + tc + 16 * j] = acc[i][j];
        }
    }
}

// ---------------- el/er per (node, head) ------------------------------------
__global__ __launch_bounds__(256) void k_elr(const float* __restrict__ fs,
                                             const float* __restrict__ al,
                                             const float* __restrict__ ar,
                                             float* __restrict__ el,
                                             float* __restrict__ er) {
    int i = blockIdx.x * blockDim.x + threadIdx.x;  // node*NH + h
    if (i >= NN * NH) return;
    int h = i & 3;
    const float* p = fs + (size_t)i * DH;
    float sl = 0.f, sr = 0.f;
#pragma unroll
    for (int d = 0; d < DH; d += 4) {
        float4 v = *(const float4*)&p[d];
        float4 l = *(const float4*)&al[h * DH + d];
        float4 r = *(const float4*)&ar[h * DH + d];
        sl += v.x * l.x + v.y * l.y + v.z * l.z + v.w * l.w;
        sr += v.x * r.x + v.y * r.y + v.z * r.z + v.w * r.w;
    }
    el[i] = sl;
    er[i] = sr;
}

// ---------------- degree histogram ------------------------------------------
__global__ __launch_bounds__(256) void k_deg(const int* __restrict__ dst,
                                             int* __restrict__ deg) {
    int e = blockIdx.x * blockDim.x + threadIdx.x;
    if (e >= NE) return;
    atomicAdd(&deg[dst[e]], 1);
}

// ---------------- exclusive scan (single block) ------------------------------
__global__ __launch_bounds__(1024) void k_scan(const int* __restrict__ deg,
                                               int* __restrict__ row_off) {
    __shared__ int wsum[16];
    __shared__ int carry_s;
    int t = threadIdx.x;
    int lane = t & 63, w = t >> 6;
    if (t == 0) carry_s = 0;
    __syncthreads();
    for (int base = 0; base < NN; base += 1024) {
        int idx = base + t;
        int v = (idx < NN) ? deg[idx] : 0;
        int x = v;
#pragma unroll
        for (int off = 1; off < 64; off <<= 1) {
            int y = __shfl_up(x, off);
            if (lane >= off) x += y;
        }
        if (lane == 63) wsum[w] = x;
        __syncthreads();
        if (w == 0) {
            int s = (lane < 16) ? wsum[lane] : 0;
#pragma unroll
            for (int off = 1; off < 16; off <<= 1) {
                int y = __shfl_up(s, off);
                if (lane >= off) s += y;
            }
            if (lane < 16) wsum[lane] = s;
        }
        __syncthreads();
        int incl = x + (w > 0 ? wsum[w - 1] : 0);
        int excl = incl - v + carry_s;
        if (idx < NN) row_off[idx] = excl;
        __syncthreads();
        if (t == 1023) carry_s += incl;   // incl at t==1023 == chunk total
        __syncthreads();
    }
    if (t == 0) row_off[NN] = carry_s;
}

// ---------------- scatter: edge -> CSR slot ----------------------------------
__global__ __launch_bounds__(256) void k_scatter(const int* __restrict__ src,
                                                 const int* __restrict__ dst,
                                                 int* __restrict__ cursor,
                                                 int* __restrict__ esrc) {
    int e = blockIdx.x * blockDim.x + threadIdx.x;
    if (e >= NE) return;
    int d = dst[e];
    int pos = atomicAdd(&cursor[d], 1);
    esrc[pos] = src[e];
}

// ---------------- aggregate: one wave per dst node ---------------------------
__global__ __launch_bounds__(256) void k_agg(const int* __restrict__ row_off,
                                             const int* __restrict__ esrc,
                                             const float* __restrict__ el,
                                             const float* __restrict__ er,
                                             const float* __restrict__ fs,
                                             float* __restrict__ out) {
    int gid = blockIdx.x * blockDim.x + threadIdx.x;
    int node = gid >> 6;
    int lane = gid & 63;
    if (node >= NN) return;
    int beg = row_off[node];
    int end = row_off[node + 1];
    int h = lane >> 4;       // 0..3
    int dd = lane * 2;       // 0..126

    float rr = er[node * 4 + h];

    // pass A: segment max of leaky-relu scores for this head
    float m = -INFINITY;
    for (int k = beg; k < end; k++) {
        int s = esrc[k];
        float sc = el[s * 4 + h] + rr;
        sc = sc > 0.f ? sc : NEG_SLOPE * sc;
        m = fmaxf(m, sc);
    }
    if (end == beg) m = 0.f;

    // pass B: exp, denom, weighted feature accumulate
    float den = 0.f, a0 = 0.f, a1 = 0.f;
    for (int k = beg; k < end; k++) {
        int s = esrc[k];
        float sc = el[s * 4 + h] + rr;
        sc = sc > 0.f ? sc : NEG_SLOPE * sc;
        float ee = __expf(sc - m);
        den += ee;
        float2 v = *(const float2*)&fs[(size_t)s * NHD + dd];
        a0 += ee * v.x;
        a1 += ee * v.y;
    }
    float inv = den > 0.f ? 1.0f / den : 0.f;
    out[(size_t)node * NHD + dd] = a0 * inv;
    out[(size_t)node * NHD + dd + 1] = a1 * inv;
}

extern "C" void kernel_launch(void* const* d_in, const int* in_sizes, int n_in,
                              void* d_out, int out_size, void* d_ws, size_t ws_size,
                              hipStream_t stream) {
    const float* feat = (const float*)d_in[0];
    const int* src = (const int*)d_in[1];
    const int* dst = (const int*)d_in[2];
    const float* W = (const float*)d_in[3];
    const float* al = (const float*)d_in[4];
    const float* ar = (const float*)d_in[5];
    float* out = (float*)d_out;

    char* ws = (char*)d_ws;
    float* fs = (float*)ws;                          ws += (size_t)NN * NHD * 4;  // 51.2 MB
    float* el = (float*)ws;                          ws += (size_t)NN * NH * 4;
    float* er = (float*)ws;                          ws += (size_t)NN * NH * 4;
    int* deg = (int*)ws;                             ws += (size_t)NN * 4;
    int* row_off = (int*)ws;                         ws += (size_t)(NN + 1) * 4;
    int* cursor = (int*)ws;                          ws += (size_t)NN * 4;
    int* esrc = (int*)ws;                            ws += (size_t)NE * 4;        // 6.4 MB

    hipMemsetAsync(deg, 0, (size_t)NN * sizeof(int), stream);

    k_gemm<<<(NN + 63) / 64, 256, 0, stream>>>(feat, W, fs);
    k_elr<<<(NN * NH + 255) / 256, 256, 0, stream>>>(fs, al, ar, el, er);
    k_deg<<<(NE + 255) / 256, 256, 0, stream>>>(dst, deg);
    k_scan<<<1, 1024, 0, stream>>>(deg, row_off);
    hipMemcpyAsync(cursor, row_off, (size_t)NN * sizeof(int),
                   hipMemcpyDeviceToDevice, stream);
    k_scatter<<<(NE + 255) / 256, 256, 0, stream>>>(src, dst, cursor, esrc);
    k_agg<<<(NN * 64 + 255) / 256, 256, 0, stream>>>(row_off, esrc, el, er, fs, out);
}

// Round 3
// 324.554 us; speedup vs baseline: 5.6387x; 2.0947x over previous
//
#include <hip/hip_runtime.h>
#include <math.h>

#define NN 100000
#define NE 1600000
#define INF_ 256
#define NH 4
#define DH 32
#define NHD 128
#define NEG_SLOPE 0.2f

typedef __attribute__((ext_vector_type(8))) short bf16x8;
typedef __attribute__((ext_vector_type(4))) float f32x4;

__device__ __forceinline__ unsigned short f2bf(float f) {
    unsigned u = __float_as_uint(f);
    u += 0x7FFFu + ((u >> 16) & 1u);   // round-to-nearest-even
    return (unsigned short)(u >> 16);
}

// ======== GEMM: feat[NN,256] x W[128,256]^T -> fsb[NN,128] (bf16) ============
// 128x128 tile, 4 waves (2x2), 16x16x32 bf16 MFMA, BK=32, XOR-swizzled LDS.
__global__ __launch_bounds__(256) void k_gemm(const float* __restrict__ feat,
                                              const float* __restrict__ W,
                                              unsigned short* __restrict__ fsb) {
    __shared__ short sA[128 * 64];   // row stride 64 shorts (128 B), 8 granules/row
    __shared__ short sB[128 * 64];
    const int t = threadIdx.x;
    const int brow = blockIdx.x * 128;
    const int wid = t >> 6, lane = t & 63;
    const int wr = wid >> 1, wc = wid & 1;
    const int lg = lane >> 4;    // k-group 0..3
    const int lr = lane & 15;

    f32x4 acc[4][4];
#pragma unroll
    for (int m = 0; m < 4; m++)
#pragma unroll
        for (int n = 0; n < 4; n++) acc[m][n] = (f32x4){0.f, 0.f, 0.f, 0.f};

    const int srow = t >> 1;         // 0..127 staging row
    const int cb = (t & 1) * 16;     // 0 or 16
    const int g0 = cb >> 3;          // granule 0 or 2
    const int p0 = (g0 ^ (srow & 7));
    const int p1 = ((g0 + 1) ^ (srow & 7));
    const int grow = brow + srow;
    const bool arow_ok = (grow < NN);

    for (int k0 = 0; k0 < INF_; k0 += 32) {
        // ---- stage A (feat), fp32 -> bf16 ----
        {
            float fv[16];
            if (arow_ok) {
                const float4* pa = (const float4*)&feat[(size_t)grow * INF_ + k0 + cb];
                *(float4*)&fv[0]  = pa[0];
                *(float4*)&fv[4]  = pa[1];
                *(float4*)&fv[8]  = pa[2];
                *(float4*)&fv[12] = pa[3];
            } else {
#pragma unroll
                for (int j = 0; j < 16; j++) fv[j] = 0.f;
            }
            short sv[16];
#pragma unroll
            for (int j = 0; j < 16; j++) sv[j] = (short)f2bf(fv[j]);
            *(bf16x8*)&sA[srow * 64 + p0 * 8] = *(const bf16x8*)&sv[0];
            *(bf16x8*)&sA[srow * 64 + p1 * 8] = *(const bf16x8*)&sv[8];
        }
        // ---- stage B (W), fp32 -> bf16 ----
        {
            float fv[16];
            const float4* pb = (const float4*)&W[(size_t)srow * INF_ + k0 + cb];
            *(float4*)&fv[0]  = pb[0];
            *(float4*)&fv[4]  = pb[1];
            *(float4*)&fv[8]  = pb[2];
            *(float4*)&fv[12] = pb[3];
            short sv[16];
#pragma unroll
            for (int j = 0; j < 16; j++) sv[j] = (short)f2bf(fv[j]);
            *(bf16x8*)&sB[srow * 64 + p0 * 8] = *(const bf16x8*)&sv[0];
            *(bf16x8*)&sB[srow * 64 + p1 * 8] = *(const bf16x8*)&sv[8];
        }
        __syncthreads();
        // ---- fragments + MFMA ----
        bf16x8 aF[4], bF[4];
#pragma unroll
        for (int m = 0; m < 4; m++) {
            int r = wr * 64 + m * 16 + lr;
            aF[m] = *(const bf16x8*)&sA[r * 64 + ((lg ^ (r & 7)) * 8)];
        }
#pragma unroll
        for (int n = 0; n < 4; n++) {
            int r = wc * 64 + n * 16 + lr;
            bF[n] = *(const bf16x8*)&sB[r * 64 + ((lg ^ (r & 7)) * 8)];
        }
#pragma unroll
        for (int m = 0; m < 4; m++)
#pragma unroll
            for (int n = 0; n < 4; n++)
                acc[m][n] = __builtin_amdgcn_mfma_f32_16x16x32_bf16(aF[m], bF[n], acc[m][n], 0, 0, 0);
        __syncthreads();
    }
    // ---- epilogue: C/D layout col=lane&15, row=(lane>>4)*4+reg ----
#pragma unroll
    for (int m = 0; m < 4; m++) {
#pragma unroll
        for (int n = 0; n < 4; n++) {
#pragma unroll
            for (int r = 0; r < 4; r++) {
                int gr = brow + wr * 64 + m * 16 + lg * 4 + r;
                if (gr < NN)
                    fsb[(size_t)gr * NHD + wc * 64 + n * 16 + lr] = f2bf(acc[m][n][r]);
            }
        }
    }
}

// ======== el/er per (node, head) from bf16 fsb ===============================
__global__ __launch_bounds__(256) void k_elr(const unsigned short* __restrict__ fsb,
                                             const float* __restrict__ al,
                                             const float* __restrict__ ar,
                                             float* __restrict__ el,
                                             float* __restrict__ er) {
    int i = blockIdx.x * blockDim.x + threadIdx.x;  // node*NH + h
    if (i >= NN * NH) return;
    int h = i & 3;
    const unsigned short* p = fsb + (size_t)(i >> 2) * NHD + h * DH;
    float sl = 0.f, sr = 0.f;
#pragma unroll
    for (int j = 0; j < 4; j++) {
        uint4 q = *((const uint4*)p + j);
        unsigned uu[4] = {q.x, q.y, q.z, q.w};
#pragma unroll
        for (int c = 0; c < 4; c++) {
            int d = j * 8 + c * 2;
            float lo = __uint_as_float(uu[c] << 16);
            float hi = __uint_as_float(uu[c] & 0xFFFF0000u);
            sl += lo * al[h * DH + d] + hi * al[h * DH + d + 1];
            sr += lo * ar[h * DH + d] + hi * ar[h * DH + d + 1];
        }
    }
    el[i] = sl;
    er[i] = sr;
}

// ======== degree histogram ===================================================
__global__ __launch_bounds__(256) void k_deg(const int* __restrict__ dst,
                                             int* __restrict__ deg) {
    int e = blockIdx.x * blockDim.x + threadIdx.x;
    if (e >= NE) return;
    atomicAdd(&deg[dst[e]], 1);
}

// ======== two-level exclusive scan ==========================================
__global__ __launch_bounds__(1024) void k_scan1(const int* __restrict__ deg,
                                                int* __restrict__ row_off,
                                                int* __restrict__ bsum) {
    __shared__ int wsum[16];
    int t = threadIdx.x;
    int i = blockIdx.x * 1024 + t;
    int lane = t & 63, w = t >> 6;
    int v = (i < NN) ? deg[i] : 0;
    int x = v;
#pragma unroll
    for (int off = 1; off < 64; off <<= 1) {
        int y = __shfl_up(x, off);
        if (lane >= off) x += y;
    }
    if (lane == 63) wsum[w] = x;
    __syncthreads();
    if (w == 0) {
        int s = (lane < 16) ? wsum[lane] : 0;
#pragma unroll
        for (int off = 1; off < 16; off <<= 1) {
            int y = __shfl_up(s, off);
            if (lane >= off) s += y;
        }
        if (lane < 16) wsum[lane] = s;
    }
    __syncthreads();
    int incl = x + (w > 0 ? wsum[w - 1] : 0);
    if (i < NN) row_off[i] = incl - v;     // block-local exclusive
    if (t == 1023) bsum[blockIdx.x] = incl;
}

__global__ __launch_bounds__(128) void k_scan2(int* __restrict__ bsum,
                                               int* __restrict__ row_off) {
    __shared__ int s[128];
    int t = threadIdx.x;
    int v = (t < 98) ? bsum[t] : 0;
    s[t] = v;
    __syncthreads();
#pragma unroll
    for (int off = 1; off < 128; off <<= 1) {
        int y = (t >= off) ? s[t - off] : 0;
        __syncthreads();
        if (t >= off) s[t] += y;
        __syncthreads();
    }
    if (t < 98) bsum[t] = (t == 0) ? 0 : s[t - 1];  // exclusive block offsets
    if (t == 0) row_off[NN] = s[97];
}

__global__ __launch_bounds__(1024) void k_scan3(int* __restrict__ row_off,
                                                const int* __restrict__ bsum,
                                                int* __restrict__ cursor) {
    int i = blockIdx.x * 1024 + threadIdx.x;
    if (i >= NN) return;
    int e = row_off[i] + bsum[i >> 10];
    row_off[i] = e;
    cursor[i] = e;
}

// ======== scatter: edge -> CSR slot =========================================
__global__ __launch_bounds__(256) void k_scatter(const int* __restrict__ src,
                                                 const int* __restrict__ dst,
                                                 int* __restrict__ cursor,
                                                 int* __restrict__ esrc) {
    int e = blockIdx.x * blockDim.x + threadIdx.x;
    if (e >= NE) return;
    int d = dst[e];
    int pos = atomicAdd(&cursor[d], 1);
    esrc[pos] = src[e];
}

// ======== aggregate: wave per dst node, single pass (no max needed) ==========
__global__ __launch_bounds__(256) void k_agg(const int* __restrict__ row_off,
                                             const int* __restrict__ esrc,
                                             const float* __restrict__ el,
                                             const float* __restrict__ er,
                                             const unsigned* __restrict__ fsb32,
                                             float* __restrict__ out) {
    int gid = blockIdx.x * blockDim.x + threadIdx.x;
    int node = gid >> 6;
    int lane = gid & 63;
    if (node >= NN) return;
    int beg = row_off[node];
    int end = row_off[node + 1];
    int h = lane >> 4;
    float rr = er[node * 4 + h];
    float den = 0.f, a0 = 0.f, a1 = 0.f;

#define STEP(eV, vV)                                          \
    {                                                         \
        float sc = (eV) + rr;                                 \
        sc = sc > 0.f ? sc : NEG_SLOPE * sc;                  \
        float ee = __expf(sc);                                \
        den += ee;                                            \
        a0 += ee * __uint_as_float((vV) << 16);               \
        a1 += ee * __uint_as_float((vV) & 0xFFFF0000u);       \
    }

    int k = beg;
    for (; k + 4 <= end; k += 4) {
        int s0 = esrc[k], s1 = esrc[k + 1], s2 = esrc[k + 2], s3 = esrc[k + 3];
        unsigned v0 = fsb32[(size_t)s0 * 64 + lane];
        unsigned v1 = fsb32[(size_t)s1 * 64 + lane];
        unsigned v2 = fsb32[(size_t)s2 * 64 + lane];
        unsigned v3 = fsb32[(size_t)s3 * 64 + lane];
        float e0 = el[s0 * 4 + h], e1 = el[s1 * 4 + h];
        float e2 = el[s2 * 4 + h], e3 = el[s3 * 4 + h];
        STEP(e0, v0) STEP(e1, v1) STEP(e2, v2) STEP(e3, v3)
    }
    for (; k < end; k++) {
        int s = esrc[k];
        unsigned v = fsb32[(size_t)s * 64 + lane];
        float eV = el[s * 4 + h];
        STEP(eV, v)
    }
#undef STEP

    float inv = den > 0.f ? 1.0f / den : 0.f;
    float2 o;
    o.x = a0 * inv;
    o.y = a1 * inv;
    *(float2*)&out[(size_t)node * NHD + lane * 2] = o;
}

extern "C" void kernel_launch(void* const* d_in, const int* in_sizes, int n_in,
                              void* d_out, int out_size, void* d_ws, size_t ws_size,
                              hipStream_t stream) {
    const float* feat = (const float*)d_in[0];
    const int* src = (const int*)d_in[1];
    const int* dst = (const int*)d_in[2];
    const float* W = (const float*)d_in[3];
    const float* al = (const float*)d_in[4];
    const float* ar = (const float*)d_in[5];
    float* out = (float*)d_out;

    char* ws = (char*)d_ws;
    unsigned short* fsb = (unsigned short*)ws;  ws += (size_t)NN * NHD * 2;   // 25.6 MB
    float* el = (float*)ws;                     ws += (size_t)NN * NH * 4;
    float* er = (float*)ws;                     ws += (size_t)NN * NH * 4;
    int* deg = (int*)ws;                        ws += (size_t)NN * 4;
    int* row_off = (int*)ws;                    ws += (size_t)(NN + 1) * 4;
    int* bsum = (int*)ws;                       ws += 128 * 4;
    int* cursor = (int*)ws;                     ws += (size_t)NN * 4;
    int* esrc = (int*)ws;                       ws += (size_t)NE * 4;          // 6.4 MB

    hipMemsetAsync(deg, 0, (size_t)NN * sizeof(int), stream);

    k_gemm<<<(NN + 127) / 128, 256, 0, stream>>>(feat, W, fsb);
    k_elr<<<(NN * NH + 255) / 256, 256, 0, stream>>>(fsb, al, ar, el, er);
    k_deg<<<(NE + 255) / 256, 256, 0, stream>>>(dst, deg);
    k_scan1<<<(NN + 1023) / 1024, 1024, 0, stream>>>(deg, row_off, bsum);
    k_scan2<<<1, 128, 0, stream>>>(bsum, row_off);
    k_scan3<<<(NN + 1023) / 1024, 1024, 0, stream>>>(row_off, bsum, cursor);
    k_scatter<<<(NE + 255) / 256, 256, 0, stream>>>(src, dst, cursor, esrc);
    k_agg<<<(NN * 64 + 255) / 256, 256, 0, stream>>>(row_off, esrc, el, er,
                                                     (const unsigned*)fsb, out);
}

// Round 4
// 177.031 us; speedup vs baseline: 10.3376x; 1.8333x over previous
//
#include <hip/hip_runtime.h>
#include <math.h>

#define NN 100000
#define NE 1600000
#define INF_ 256
#define NH 4
#define DH 32
#define NHD 128
#define NEG_SLOPE 0.2f

#define NB 391       // coarse buckets = ceil(NN / 256)
#define EPB 8192     // edges per pass-A block (256 thr x 32)
#define NBLK_A 196   // ceil(NE / EPB)
#define NHIST (NB * NBLK_A)

typedef __attribute__((ext_vector_type(8))) short bf16x8;
typedef __attribute__((ext_vector_type(4))) float f32x4;

__device__ __forceinline__ unsigned short f2bf(float f) {
    unsigned u = __float_as_uint(f);
    u += 0x7FFFu + ((u >> 16) & 1u);   // round-to-nearest-even
    return (unsigned short)(u >> 16);
}

// ======== GEMM: feat[NN,256] x W[128,256]^T -> fsb[NN,128] (bf16) ============
__global__ __launch_bounds__(256) void k_gemm(const float* __restrict__ feat,
                                              const float* __restrict__ W,
                                              unsigned short* __restrict__ fsb) {
    __shared__ short sA[128 * 64];
    __shared__ short sB[128 * 64];
    const int t = threadIdx.x;
    const int brow = blockIdx.x * 128;
    const int wid = t >> 6, lane = t & 63;
    const int wr = wid >> 1, wc = wid & 1;
    const int lg = lane >> 4;
    const int lr = lane & 15;

    f32x4 acc[4][4];
#pragma unroll
    for (int m = 0; m < 4; m++)
#pragma unroll
        for (int n = 0; n < 4; n++) acc[m][n] = (f32x4){0.f, 0.f, 0.f, 0.f};

    const int srow = t >> 1;
    const int cb = (t & 1) * 16;
    const int g0 = cb >> 3;
    const int p0 = (g0 ^ (srow & 7));
    const int p1 = ((g0 + 1) ^ (srow & 7));
    const int grow = brow + srow;
    const bool arow_ok = (grow < NN);

    for (int k0 = 0; k0 < INF_; k0 += 32) {
        {
            float fv[16];
            if (arow_ok) {
                const float4* pa = (const float4*)&feat[(size_t)grow * INF_ + k0 + cb];
                *(float4*)&fv[0]  = pa[0];
                *(float4*)&fv[4]  = pa[1];
                *(float4*)&fv[8]  = pa[2];
                *(float4*)&fv[12] = pa[3];
            } else {
#pragma unroll
                for (int j = 0; j < 16; j++) fv[j] = 0.f;
            }
            short sv[16];
#pragma unroll
            for (int j = 0; j < 16; j++) sv[j] = (short)f2bf(fv[j]);
            *(bf16x8*)&sA[srow * 64 + p0 * 8] = *(const bf16x8*)&sv[0];
            *(bf16x8*)&sA[srow * 64 + p1 * 8] = *(const bf16x8*)&sv[8];
        }
        {
            float fv[16];
            const float4* pb = (const float4*)&W[(size_t)srow * INF_ + k0 + cb];
            *(float4*)&fv[0]  = pb[0];
            *(float4*)&fv[4]  = pb[1];
            *(float4*)&fv[8]  = pb[2];
            *(float4*)&fv[12] = pb[3];
            short sv[16];
#pragma unroll
            for (int j = 0; j < 16; j++) sv[j] = (short)f2bf(fv[j]);
            *(bf16x8*)&sB[srow * 64 + p0 * 8] = *(const bf16x8*)&sv[0];
            *(bf16x8*)&sB[srow * 64 + p1 * 8] = *(const bf16x8*)&sv[8];
        }
        __syncthreads();
        bf16x8 aF[4], bF[4];
#pragma unroll
        for (int m = 0; m < 4; m++) {
            int r = wr * 64 + m * 16 + lr;
            aF[m] = *(const bf16x8*)&sA[r * 64 + ((lg ^ (r & 7)) * 8)];
        }
#pragma unroll
        for (int n = 0; n < 4; n++) {
            int r = wc * 64 + n * 16 + lr;
            bF[n] = *(const bf16x8*)&sB[r * 64 + ((lg ^ (r & 7)) * 8)];
        }
#pragma unroll
        for (int m = 0; m < 4; m++)
#pragma unroll
            for (int n = 0; n < 4; n++)
                acc[m][n] = __builtin_amdgcn_mfma_f32_16x16x32_bf16(aF[m], bF[n], acc[m][n], 0, 0, 0);
        __syncthreads();
    }
#pragma unroll
    for (int m = 0; m < 4; m++) {
#pragma unroll
        for (int n = 0; n < 4; n++) {
#pragma unroll
            for (int r = 0; r < 4; r++) {
                int gr = brow + wr * 64 + m * 16 + lg * 4 + r;
                if (gr < NN)
                    fsb[(size_t)gr * NHD + wc * 64 + n * 16 + lr] = f2bf(acc[m][n][r]);
            }
        }
    }
}

// ======== el/er per (node, head) =============================================
__global__ __launch_bounds__(256) void k_elr(const unsigned short* __restrict__ fsb,
                                             const float* __restrict__ al,
                                             const float* __restrict__ ar,
                                             float* __restrict__ el,
                                             float* __restrict__ er) {
    int i = blockIdx.x * blockDim.x + threadIdx.x;
    if (i >= NN * NH) return;
    int h = i & 3;
    const unsigned short* p = fsb + (size_t)(i >> 2) * NHD + h * DH;
    float sl = 0.f, sr = 0.f;
#pragma unroll
    for (int j = 0; j < 4; j++) {
        uint4 q = *((const uint4*)p + j);
        unsigned uu[4] = {q.x, q.y, q.z, q.w};
#pragma unroll
        for (int c = 0; c < 4; c++) {
            int d = j * 8 + c * 2;
            float lo = __uint_as_float(uu[c] << 16);
            float hi = __uint_as_float(uu[c] & 0xFFFF0000u);
            sl += lo * al[h * DH + d] + hi * al[h * DH + d + 1];
            sr += lo * ar[h * DH + d] + hi * ar[h * DH + d + 1];
        }
    }
    el[i] = sl;
    er[i] = sr;
}

// ======== pass A1: per-block coarse-bucket histogram ========================
__global__ __launch_bounds__(256) void k_hist(const int* __restrict__ dst,
                                              int* __restrict__ histT) {
    __shared__ int lh[NB];
    int t = threadIdx.x;
    for (int b = t; b < NB; b += 256) lh[b] = 0;
    __syncthreads();
    int base = blockIdx.x * EPB;
#pragma unroll
    for (int j = 0; j < 32; j++) {
        int e = base + j * 256 + t;
        if (e < NE) atomicAdd(&lh[dst[e] >> 8], 1);
    }
    __syncthreads();
    for (int b = t; b < NB; b += 256) histT[b * NBLK_A + blockIdx.x] = lh[b];
}

// ======== generic exclusive scan (3 kernels) ================================
__global__ __launch_bounds__(1024) void k_scan1(int* __restrict__ data,
                                                int* __restrict__ bsum, int n) {
    __shared__ int wsum[16];
    int t = threadIdx.x;
    int i = blockIdx.x * 1024 + t;
    int lane = t & 63, w = t >> 6;
    int v = (i < n) ? data[i] : 0;
    int x = v;
#pragma unroll
    for (int off = 1; off < 64; off <<= 1) {
        int y = __shfl_up(x, off);
        if (lane >= off) x += y;
    }
    if (lane == 63) wsum[w] = x;
    __syncthreads();
    if (w == 0) {
        int s = (lane < 16) ? wsum[lane] : 0;
#pragma unroll
        for (int off = 1; off < 16; off <<= 1) {
            int y = __shfl_up(s, off);
            if (lane >= off) s += y;
        }
        if (lane < 16) wsum[lane] = s;
    }
    __syncthreads();
    int incl = x + (w > 0 ? wsum[w - 1] : 0);
    if (i < n) data[i] = incl - v;
    if (t == 1023) bsum[blockIdx.x] = incl;
}

__global__ __launch_bounds__(128) void k_scan2(int* __restrict__ bsum, int nb) {
    __shared__ int s[128];
    int t = threadIdx.x;
    int v = (t < nb) ? bsum[t] : 0;
    s[t] = v;
    __syncthreads();
#pragma unroll
    for (int off = 1; off < 128; off <<= 1) {
        int y = (t >= off) ? s[t - off] : 0;
        __syncthreads();
        if (t >= off) s[t] += y;
        __syncthreads();
    }
    if (t < nb) bsum[t] = (t == 0) ? 0 : s[t - 1];
}

__global__ __launch_bounds__(1024) void k_scan3(int* __restrict__ data,
                                                const int* __restrict__ bsum, int n) {
    int i = blockIdx.x * 1024 + threadIdx.x;
    if (i >= n) return;
    data[i] += bsum[i >> 10];
}

// ======== pass A2: scatter packed (dst,src) into bucket order ================
__global__ __launch_bounds__(256) void k_bin(const int* __restrict__ src,
                                             const int* __restrict__ dst,
                                             const int* __restrict__ histT,
                                             unsigned long long* __restrict__ packed) {
    __shared__ int lc[NB];
    int t = threadIdx.x;
    for (int b = t; b < NB; b += 256) lc[b] = histT[b * NBLK_A + blockIdx.x];
    __syncthreads();
    int base = blockIdx.x * EPB;
#pragma unroll
    for (int j = 0; j < 32; j++) {
        int e = base + j * 256 + t;
        if (e < NE) {
            int d = dst[e], s = src[e];
            int pos = atomicAdd(&lc[d >> 8], 1);
            packed[pos] = ((unsigned long long)(unsigned)d << 32) | (unsigned)s;
        }
    }
}

// ======== pass B: per-bucket exact sort; also emits row_off ==================
__global__ __launch_bounds__(256) void k_sort(const int* __restrict__ histT,
                                              const unsigned long long* __restrict__ packed,
                                              int* __restrict__ row_off,
                                              int* __restrict__ esrc) {
    __shared__ int lh[256];
    __shared__ int cur[256];
    __shared__ int wsum[4];
    int b = blockIdx.x, t = threadIdx.x;
    int beg = histT[b * NBLK_A];
    int end = (b + 1 < NB) ? histT[(b + 1) * NBLK_A] : NE;
    lh[t] = 0;
    __syncthreads();
    for (int k = beg + t; k < end; k += 256) {
        int d = (int)(packed[k] >> 32);
        atomicAdd(&lh[d & 255], 1);
    }
    __syncthreads();
    int v = lh[t];
    int lane = t & 63, w = t >> 6;
    int x = v;
#pragma unroll
    for (int off = 1; off < 64; off <<= 1) {
        int y = __shfl_up(x, off);
        if (lane >= off) x += y;
    }
    if (lane == 63) wsum[w] = x;
    __syncthreads();
    int add = 0;
    for (int j = 0; j < w; j++) add += wsum[j];
    int excl = beg + add + x - v;
    int node = (b << 8) + t;
    if (node < NN) row_off[node] = excl;
    cur[t] = excl;
    __syncthreads();
    for (int k = beg + t; k < end; k += 256) {
        unsigned long long p = packed[k];
        int d = (int)(p >> 32);
        int s = (int)(unsigned)p;
        int pos = atomicAdd(&cur[d & 255], 1);
        esrc[pos] = s;
    }
    if (b == NB - 1 && t == 0) row_off[NN] = NE;
}

// ======== aggregate: wave per dst node, single pass ==========================
__global__ __launch_bounds__(256) void k_agg(const int* __restrict__ row_off,
                                             const int* __restrict__ esrc,
                                             const float* __restrict__ el,
                                             const float* __restrict__ er,
                                             const unsigned* __restrict__ fsb32,
                                             float* __restrict__ out) {
    int gid = blockIdx.x * blockDim.x + threadIdx.x;
    int node = gid >> 6;
    int lane = gid & 63;
    if (node >= NN) return;
    int beg = row_off[node];
    int end = row_off[node + 1];
    int h = lane >> 4;
    float rr = er[node * 4 + h];
    float den = 0.f, a0 = 0.f, a1 = 0.f;

#define STEP(eV, vV)                                          \
    {                                                         \
        float sc = (eV) + rr;                                 \
        sc = sc > 0.f ? sc : NEG_SLOPE * sc;                  \
        float ee = __expf(sc);                                \
        den += ee;                                            \
        a0 += ee * __uint_as_float((vV) << 16);               \
        a1 += ee * __uint_as_float((vV) & 0xFFFF0000u);       \
    }

    int k = beg;
    for (; k + 4 <= end; k += 4) {
        int s0 = esrc[k], s1 = esrc[k + 1], s2 = esrc[k + 2], s3 = esrc[k + 3];
        unsigned v0 = fsb32[(size_t)s0 * 64 + lane];
        unsigned v1 = fsb32[(size_t)s1 * 64 + lane];
        unsigned v2 = fsb32[(size_t)s2 * 64 + lane];
        unsigned v3 = fsb32[(size_t)s3 * 64 + lane];
        float e0 = el[s0 * 4 + h], e1 = el[s1 * 4 + h];
        float e2 = el[s2 * 4 + h], e3 = el[s3 * 4 + h];
        STEP(e0, v0) STEP(e1, v1) STEP(e2, v2) STEP(e3, v3)
    }
    for (; k < end; k++) {
        int s = esrc[k];
        unsigned v = fsb32[(size_t)s * 64 + lane];
        float eV = el[s * 4 + h];
        STEP(eV, v)
    }
#undef STEP

    float inv = den > 0.f ? 1.0f / den : 0.f;
    float2 o;
    o.x = a0 * inv;
    o.y = a1 * inv;
    *(float2*)&out[(size_t)node * NHD + lane * 2] = o;
}

extern "C" void kernel_launch(void* const* d_in, const int* in_sizes, int n_in,
                              void* d_out, int out_size, void* d_ws, size_t ws_size,
                              hipStream_t stream) {
    const float* feat = (const float*)d_in[0];
    const int* src = (const int*)d_in[1];
    const int* dst = (const int*)d_in[2];
    const float* W = (const float*)d_in[3];
    const float* al = (const float*)d_in[4];
    const float* ar = (const float*)d_in[5];
    float* out = (float*)d_out;

    char* ws = (char*)d_ws;
    unsigned short* fsb = (unsigned short*)ws;        ws += (size_t)NN * NHD * 2;   // 25.6 MB
    unsigned long long* packed = (unsigned long long*)ws; ws += (size_t)NE * 8;     // 12.8 MB
    int* esrc = (int*)ws;                             ws += (size_t)NE * 4;         // 6.4 MB
    float* el = (float*)ws;                           ws += (size_t)NN * NH * 4;
    float* er = (float*)ws;                           ws += (size_t)NN * NH * 4;
    int* row_off = (int*)ws;                          ws += (size_t)(NN + 1) * 4;
    int* histT = (int*)ws;                            ws += (size_t)NHIST * 4;
    int* bsum = (int*)ws;                             ws += 128 * 4;

    const int scan_blocks = (NHIST + 1023) / 1024;    // 75

    k_gemm<<<(NN + 127) / 128, 256, 0, stream>>>(feat, W, fsb);
    k_elr<<<(NN * NH + 255) / 256, 256, 0, stream>>>(fsb, al, ar, el, er);
    k_hist<<<NBLK_A, 256, 0, stream>>>(dst, histT);
    k_scan1<<<scan_blocks, 1024, 0, stream>>>(histT, bsum, NHIST);
    k_scan2<<<1, 128, 0, stream>>>(bsum, scan_blocks);
    k_scan3<<<scan_blocks, 1024, 0, stream>>>(histT, bsum, NHIST);
    k_bin<<<NBLK_A, 256, 0, stream>>>(src, dst, histT, packed);
    k_sort<<<NB, 256, 0, stream>>>(histT, packed, row_off, esrc);
    k_agg<<<(NN * 64 + 255) / 256, 256, 0, stream>>>(row_off, esrc, el, er,
                                                     (const unsigned*)fsb, out);
}

// Round 5
// 173.252 us; speedup vs baseline: 10.5631x; 1.0218x over previous
//
#include <hip/hip_runtime.h>
#include <hip/hip_bf16.h>
#include <math.h>

#define NN 100000
#define NE 1600000
#define INF_ 256
#define NH 4
#define DH 32
#define NHD 128
#define NEG_SLOPE 0.2f

#define NB 391       // coarse buckets = ceil(NN / 256)
#define EPB 8192     // edges per pass-A block (256 thr x 32)
#define NBLK_A 196   // ceil(NE / EPB)
#define NHIST (NB * NBLK_A)

typedef __attribute__((ext_vector_type(8))) short bf16x8;
typedef __attribute__((ext_vector_type(4))) float f32x4;

__device__ __forceinline__ unsigned short f2bf(float f) {
    __hip_bfloat16 b = __float2bfloat16(f);
    return *reinterpret_cast<unsigned short*>(&b);
}

// ======== W pre-convert + pre-swizzle into per-K-tile LDS images =============
// Image tile kt (16KB): row r (0..127) stride 128B; data granule g (0..3,
// k-range kt*32+g*8..+8, 8 bf16 = 16B) stored at slot g^(r&7).
__global__ __launch_bounds__(256) void k_wcvt(const float* __restrict__ W,
                                              unsigned short* __restrict__ Wimg) {
    int i = blockIdx.x * 256 + threadIdx.x;   // 0..4095
    if (i >= 4096) return;
    int kt = i >> 9;
    int r = (i >> 2) & 127;
    int g = i & 3;
    int slot = g ^ (r & 7);
    const float* s = &W[(size_t)r * INF_ + kt * 32 + g * 8];
    unsigned short tmp[8];
#pragma unroll
    for (int j = 0; j < 8; j++) tmp[j] = f2bf(s[j]);
    *(bf16x8*)&Wimg[(size_t)kt * 8192 + r * 64 + slot * 8] = *(const bf16x8*)tmp;
}

// ======== GEMM: feat[NN,256] x W[128,256]^T -> fsb[NN,128] (bf16) ============
// 128x128 tile, 4 waves (2x2), 16x16x32 bf16 MFMA, BK=32, XOR-swizzled LDS.
// B staged from pre-swizzled Wimg (no cvt); next A/B prefetched across MFMA.
__global__ __launch_bounds__(256) void k_gemm(const float* __restrict__ feat,
                                              const unsigned short* __restrict__ Wimg,
                                              unsigned short* __restrict__ fsb) {
    __shared__ short sA[128 * 64];
    __shared__ short sB[128 * 64];
    const int t = threadIdx.x;
    const int brow = blockIdx.x * 128;
    const int wid = t >> 6, lane = t & 63;
    const int wr = wid >> 1, wc = wid & 1;
    const int lg = lane >> 4;
    const int lr = lane & 15;

    f32x4 acc[4][4];
#pragma unroll
    for (int m = 0; m < 4; m++)
#pragma unroll
        for (int n = 0; n < 4; n++) acc[m][n] = (f32x4){0.f, 0.f, 0.f, 0.f};

    const int srow = t >> 1;
    const int cb = (t & 1) * 16;
    const int g0 = cb >> 3;
    const int p0 = (g0 ^ (srow & 7));
    const int p1 = ((g0 + 1) ^ (srow & 7));
    const int grow = brow + srow;
    const bool arow_ok = (grow < NN);
    const char* bimg = (const char*)Wimg;

    float fv[16];
    uint4 wv0, wv1, wv2, wv3;
    // prologue: tile 0 loads
    if (arow_ok) {
        const float4* pa = (const float4*)&feat[(size_t)grow * INF_ + cb];
        *(float4*)&fv[0] = pa[0];
        *(float4*)&fv[4] = pa[1];
        *(float4*)&fv[8] = pa[2];
        *(float4*)&fv[12] = pa[3];
    } else {
#pragma unroll
        for (int j = 0; j < 16; j++) fv[j] = 0.f;
    }
    wv0 = *(const uint4*)(bimg + t * 16);
    wv1 = *(const uint4*)(bimg + 4096 + t * 16);
    wv2 = *(const uint4*)(bimg + 8192 + t * 16);
    wv3 = *(const uint4*)(bimg + 12288 + t * 16);

    for (int kt = 0; kt < 8; kt++) {
        // ---- stage current tile from regs ----
        {
            short sv[16];
#pragma unroll
            for (int j = 0; j < 16; j++) sv[j] = (short)f2bf(fv[j]);
            *(bf16x8*)&sA[srow * 64 + p0 * 8] = *(const bf16x8*)&sv[0];
            *(bf16x8*)&sA[srow * 64 + p1 * 8] = *(const bf16x8*)&sv[8];
            char* bd = (char*)sB;
            *(uint4*)(bd + t * 16) = wv0;
            *(uint4*)(bd + 4096 + t * 16) = wv1;
            *(uint4*)(bd + 8192 + t * 16) = wv2;
            *(uint4*)(bd + 12288 + t * 16) = wv3;
        }
        __syncthreads();
        // ---- prefetch next tile (flies during frag reads + MFMA) ----
        if (kt < 7) {
            int k0 = (kt + 1) * 32;
            if (arow_ok) {
                const float4* pa = (const float4*)&feat[(size_t)grow * INF_ + k0 + cb];
                *(float4*)&fv[0] = pa[0];
                *(float4*)&fv[4] = pa[1];
                *(float4*)&fv[8] = pa[2];
                *(float4*)&fv[12] = pa[3];
            }
            const char* bsrc = bimg + (size_t)(kt + 1) * 16384;
            wv0 = *(const uint4*)(bsrc + t * 16);
            wv1 = *(const uint4*)(bsrc + 4096 + t * 16);
            wv2 = *(const uint4*)(bsrc + 8192 + t * 16);
            wv3 = *(const uint4*)(bsrc + 12288 + t * 16);
        }
        // ---- fragments + MFMA ----
        bf16x8 aF[4], bF[4];
#pragma unroll
        for (int m = 0; m < 4; m++) {
            int r = wr * 64 + m * 16 + lr;
            aF[m] = *(const bf16x8*)&sA[r * 64 + ((lg ^ (r & 7)) * 8)];
        }
#pragma unroll
        for (int n = 0; n < 4; n++) {
            int r = wc * 64 + n * 16 + lr;
            bF[n] = *(const bf16x8*)&sB[r * 64 + ((lg ^ (r & 7)) * 8)];
        }
#pragma unroll
        for (int m = 0; m < 4; m++)
#pragma unroll
            for (int n = 0; n < 4; n++)
                acc[m][n] = __builtin_amdgcn_mfma_f32_16x16x32_bf16(aF[m], bF[n], acc[m][n], 0, 0, 0);
        __syncthreads();
    }
    // ---- epilogue ----
#pragma unroll
    for (int m = 0; m < 4; m++) {
#pragma unroll
        for (int n = 0; n < 4; n++) {
#pragma unroll
            for (int r = 0; r < 4; r++) {
                int gr = brow + wr * 64 + m * 16 + lg * 4 + r;
                if (gr < NN)
                    fsb[(size_t)gr * NHD + wc * 64 + n * 16 + lr] = f2bf(acc[m][n][r]);
            }
        }
    }
}

// ======== el/er per (node, head) =============================================
__global__ __launch_bounds__(256) void k_elr(const unsigned short* __restrict__ fsb,
                                             const float* __restrict__ al,
                                             const float* __restrict__ ar,
                                             float* __restrict__ el,
                                             float* __restrict__ er) {
    int i = blockIdx.x * blockDim.x + threadIdx.x;
    if (i >= NN * NH) return;
    int h = i & 3;
    const unsigned short* p = fsb + (size_t)(i >> 2) * NHD + h * DH;
    float sl = 0.f, sr = 0.f;
#pragma unroll
    for (int j = 0; j < 4; j++) {
        uint4 q = *((const uint4*)p + j);
        unsigned uu[4] = {q.x, q.y, q.z, q.w};
#pragma unroll
        for (int c = 0; c < 4; c++) {
            int d = j * 8 + c * 2;
            float lo = __uint_as_float(uu[c] << 16);
            float hi = __uint_as_float(uu[c] & 0xFFFF0000u);
            sl += lo * al[h * DH + d] + hi * al[h * DH + d + 1];
            sr += lo * ar[h * DH + d] + hi * ar[h * DH + d + 1];
        }
    }
    el[i] = sl;
    er[i] = sr;
}

// ======== pass A1: per-block coarse-bucket histogram ========================
__global__ __launch_bounds__(256) void k_hist(const int* __restrict__ dst,
                                              int* __restrict__ histT) {
    __shared__ int lh[NB];
    int t = threadIdx.x;
    for (int b = t; b < NB; b += 256) lh[b] = 0;
    __syncthreads();
    int base = blockIdx.x * EPB;
#pragma unroll
    for (int j = 0; j < 32; j++) {
        int e = base + j * 256 + t;
        if (e < NE) atomicAdd(&lh[dst[e] >> 8], 1);
    }
    __syncthreads();
    for (int b = t; b < NB; b += 256) histT[b * NBLK_A + blockIdx.x] = lh[b];
}

// ======== two-level exclusive scan (block-local + block offsets) =============
__global__ __launch_bounds__(1024) void k_scan1(int* __restrict__ data,
                                                int* __restrict__ bsum, int n) {
    __shared__ int wsum[16];
    int t = threadIdx.x;
    int i = blockIdx.x * 1024 + t;
    int lane = t & 63, w = t >> 6;
    int v = (i < n) ? data[i] : 0;
    int x = v;
#pragma unroll
    for (int off = 1; off < 64; off <<= 1) {
        int y = __shfl_up(x, off);
        if (lane >= off) x += y;
    }
    if (lane == 63) wsum[w] = x;
    __syncthreads();
    if (w == 0) {
        int s = (lane < 16) ? wsum[lane] : 0;
#pragma unroll
        for (int off = 1; off < 16; off <<= 1) {
            int y = __shfl_up(s, off);
            if (lane >= off) s += y;
        }
        if (lane < 16) wsum[lane] = s;
    }
    __syncthreads();
    int incl = x + (w > 0 ? wsum[w - 1] : 0);
    if (i < n) data[i] = incl - v;     // block-local exclusive
    if (t == 1023) bsum[blockIdx.x] = incl;
}

__global__ __launch_bounds__(128) void k_scan2(int* __restrict__ bsum, int nb) {
    __shared__ int s[128];
    int t = threadIdx.x;
    int v = (t < nb) ? bsum[t] : 0;
    s[t] = v;
    __syncthreads();
#pragma unroll
    for (int off = 1; off < 128; off <<= 1) {
        int y = (t >= off) ? s[t - off] : 0;
        __syncthreads();
        if (t >= off) s[t] += y;
        __syncthreads();
    }
    if (t < nb) bsum[t] = (t == 0) ? 0 : s[t - 1];
}

// ======== pass A2: scatter packed (dst,src) into bucket order ================
__global__ __launch_bounds__(256) void k_bin(const int* __restrict__ src,
                                             const int* __restrict__ dst,
                                             const int* __restrict__ histT,
                                             const int* __restrict__ bsum,
                                             unsigned long long* __restrict__ packed) {
    __shared__ int lc[NB];
    int t = threadIdx.x;
    for (int b = t; b < NB; b += 256) {
        int idx = b * NBLK_A + blockIdx.x;
        lc[b] = histT[idx] + bsum[idx >> 10];
    }
    __syncthreads();
    int base = blockIdx.x * EPB;
#pragma unroll
    for (int j = 0; j < 32; j++) {
        int e = base + j * 256 + t;
        if (e < NE) {
            int d = dst[e], s = src[e];
            int pos = atomicAdd(&lc[d >> 8], 1);
            packed[pos] = ((unsigned long long)(unsigned)d << 32) | (unsigned)s;
        }
    }
}

// ======== pass B: per-bucket exact sort; also emits row_off ==================
__global__ __launch_bounds__(256) void k_sort(const int* __restrict__ histT,
                                              const int* __restrict__ bsum,
                                              const unsigned long long* __restrict__ packed,
                                              int* __restrict__ row_off,
                                              int* __restrict__ esrc) {
    __shared__ int lh[256];
    __shared__ int cur[256];
    __shared__ int wsum[4];
    int b = blockIdx.x, t = threadIdx.x;
    int i0 = b * NBLK_A;
    int beg = histT[i0] + bsum[i0 >> 10];
    int end = NE;
    if (b + 1 < NB) {
        int i1 = (b + 1) * NBLK_A;
        end = histT[i1] + bsum[i1 >> 10];
    }
    lh[t] = 0;
    __syncthreads();
    for (int k = beg + t; k < end; k += 256) {
        int d = (int)(packed[k] >> 32);
        atomicAdd(&lh[d & 255], 1);
    }
    __syncthreads();
    int v = lh[t];
    int lane = t & 63, w = t >> 6;
    int x = v;
#pragma unroll
    for (int off = 1; off < 64; off <<= 1) {
        int y = __shfl_up(x, off);
        if (lane >= off) x += y;
    }
    if (lane == 63) wsum[w] = x;
    __syncthreads();
    int add = 0;
    for (int j = 0; j < w; j++) add += wsum[j];
    int excl = beg + add + x - v;
    int node = (b << 8) + t;
    if (node < NN) row_off[node] = excl;
    cur[t] = excl;
    __syncthreads();
    for (int k = beg + t; k < end; k += 256) {
        unsigned long long p = packed[k];
        int d = (int)(p >> 32);
        int s = (int)(unsigned)p;
        int pos = atomicAdd(&cur[d & 255], 1);
        esrc[pos] = s;
    }
    if (b == NB - 1 && t == 0) row_off[NN] = NE;
}

// ======== aggregate: wave per dst node, 2 edges/wave, 8B per lane ============
__global__ __launch_bounds__(256) void k_agg(const int* __restrict__ row_off,
                                             const int* __restrict__ esrc,
                                             const float* __restrict__ el,
                                             const float* __restrict__ er,
                                             const uint2* __restrict__ fsb64,
                                             float* __restrict__ out) {
    int gid = blockIdx.x * blockDim.x + threadIdx.x;
    int node = gid >> 6;
    int lane = gid & 63;
    if (node >= NN) return;
    int half = lane >> 5;      // which edge of the pair
    int sl = lane & 31;        // feature chunk: bf16 features sl*4..sl*4+3
    int h = sl >> 3;           // head
    int beg = row_off[node];
    int end = row_off[node + 1];
    float rr = er[node * 4 + h];
    float den = 0.f, a0 = 0.f, a1 = 0.f, a2 = 0.f, a3 = 0.f;

#define STEP(eV, vV)                                           \
    {                                                          \
        float sc = (eV) + rr;                                  \
        sc = sc > 0.f ? sc : NEG_SLOPE * sc;                   \
        float ee = __expf(sc);                                 \
        den += ee;                                             \
        a0 += ee * __uint_as_float((vV).x << 16);              \
        a1 += ee * __uint_as_float((vV).x & 0xFFFF0000u);      \
        a2 += ee * __uint_as_float((vV).y << 16);              \
        a3 += ee * __uint_as_float((vV).y & 0xFFFF0000u);      \
    }

    int k = beg + half;
    for (; k + 2 < end; k += 4) {
        int s0 = esrc[k];
        int s1 = esrc[k + 2];
        uint2 v0 = fsb64[(size_t)s0 * 32 + sl];
        uint2 v1 = fsb64[(size_t)s1 * 32 + sl];
        float e0 = el[s0 * 4 + h];
        float e1 = el[s1 * 4 + h];
        STEP(e0, v0)
        STEP(e1, v1)
    }
    for (; k < end; k += 2) {
        int s = esrc[k];
        uint2 v = fsb64[(size_t)s * 32 + sl];
        float eV = el[s * 4 + h];
        STEP(eV, v)
    }
#undef STEP

    // combine the two edge-halves
    a0 += __shfl_xor(a0, 32);
    a1 += __shfl_xor(a1, 32);
    a2 += __shfl_xor(a2, 32);
    a3 += __shfl_xor(a3, 32);
    den += __shfl_xor(den, 32);

    if (half == 0) {
        float inv = den > 0.f ? 1.0f / den : 0.f;
        float4 o;
        o.x = a0 * inv;
        o.y = a1 * inv;
        o.z = a2 * inv;
        o.w = a3 * inv;
        *(float4*)&out[(size_t)node * NHD + sl * 4] = o;
    }
}

extern "C" void kernel_launch(void* const* d_in, const int* in_sizes, int n_in,
                              void* d_out, int out_size, void* d_ws, size_t ws_size,
                              hipStream_t stream) {
    const float* feat = (const float*)d_in[0];
    const int* src = (const int*)d_in[1];
    const int* dst = (const int*)d_in[2];
    const float* W = (const float*)d_in[3];
    const float* al = (const float*)d_in[4];
    const float* ar = (const float*)d_in[5];
    float* out = (float*)d_out;

    char* ws = (char*)d_ws;
    unsigned short* fsb = (unsigned short*)ws;            ws += (size_t)NN * NHD * 2;  // 25.6 MB
    unsigned long long* packed = (unsigned long long*)ws; ws += (size_t)NE * 8;        // 12.8 MB
    int* esrc = (int*)ws;                                 ws += (size_t)NE * 4;        // 6.4 MB
    float* el = (float*)ws;                               ws += (size_t)NN * NH * 4;
    float* er = (float*)ws;                               ws += (size_t)NN * NH * 4;
    int* row_off = (int*)ws;                              ws += (size_t)(NN + 1) * 4;
    int* histT = (int*)ws;                                ws += (size_t)NHIST * 4;
    int* bsum = (int*)ws;                                 ws += 128 * 4;
    unsigned short* Wimg = (unsigned short*)ws;           ws += (size_t)8 * 8192 * 2;  // 128 KB

    const int scan_blocks = (NHIST + 1023) / 1024;        // 75

    k_wcvt<<<16, 256, 0, stream>>>(W, Wimg);
    k_gemm<<<(NN + 127) / 128, 256, 0, stream>>>(feat, Wimg, fsb);
    k_elr<<<(NN * NH + 255) / 256, 256, 0, stream>>>(fsb, al, ar, el, er);
    k_hist<<<NBLK_A, 256, 0, stream>>>(dst, histT);
    k_scan1<<<scan_blocks, 1024, 0, stream>>>(histT, bsum, NHIST);
    k_scan2<<<1, 128, 0, stream>>>(bsum, scan_blocks);
    k_bin<<<NBLK_A, 256, 0, stream>>>(src, dst, histT, bsum, packed);
    k_sort<<<NB, 256, 0, stream>>>(histT, bsum, packed, row_off, esrc);
    k_agg<<<(NN * 64 + 255) / 256, 256, 0, stream>>>(row_off, esrc, el, er,
                                                     (const uint2*)fsb, out);
}